// Round 6
// baseline (523.022 us; speedup 1.0000x reference)
//
#include <hip/hip_runtime.h>
#include <cmath>

#define B_  4
#define C_  512
#define N_  16384
#define H_  8
#define D_  64
#define C3_ 1536
#define EPS 1e-6f

#define PADA 72    // bf16 tile leading pad (Sb in k_q_attn, transpose tiles)
#define PADT 136   // [j][n] transposed kv tile pad
#define PADO 132   // f32 out-transpose pad

typedef __attribute__((ext_vector_type(8))) short bf16x8;
typedef __attribute__((ext_vector_type(4))) float f32x4;

typedef const void __attribute__((address_space(1)))* gas_t;
typedef void __attribute__((address_space(3)))* las_t;

// async direct-to-LDS copy: wave-uniform LDS base, per-lane global src, 16B/lane.
__device__ __forceinline__ void gld16(const void* g, void* l) {
    __builtin_amdgcn_global_load_lds((gas_t)(unsigned long long)g,
                                     (las_t)(unsigned)(unsigned long long)l,
                                     16, 0, 0);
}

// counted vmem wait (T4): leave N newest loads in flight. Literal N only.
// Rule #18:每 VMCNT/BARRIER followed by sched_barrier(0) — hipcc can move
// instructions past inline-asm waitcnt despite the "memory" clobber.
#define VMCNT(N) asm volatile("s_waitcnt vmcnt(" #N ")" ::: "memory")
#define SCHED0() __builtin_amdgcn_sched_barrier(0)
#define BAR()    __builtin_amdgcn_s_barrier()

__device__ __forceinline__ ushort f2bf(float f) {
    union { float f; unsigned u; } c{f};
    unsigned r = (c.u + 0x7FFF + ((c.u >> 16) & 1)) >> 16;  // RNE
    return (ushort)r;
}
__device__ __forceinline__ float bf2f(ushort b) {
    union { unsigned u; float f; } c{(unsigned)b << 16};
    return c.f;
}
__device__ __forceinline__ float phi_f(float x) { return x > 0.f ? x + 1.f : __expf(x); }

// ---------------------------------------------------------------------------
// Generic transpose+cast: src f32 [R][Cc] -> dst bf16 [Cc][R].  Tiles 64x64.
// ---------------------------------------------------------------------------
__global__ __launch_bounds__(256) void k_transpose(
        const float* __restrict__ src, ushort* __restrict__ dst,
        int R, int Cc, long sStride, long dStride) {
    __shared__ ushort T[64][72];
    const long sb = (long)blockIdx.z * sStride;
    const long db = (long)blockIdx.z * dStride;
    const int c0 = blockIdx.x * 64, r0 = blockIdx.y * 64;
    const int t = threadIdx.x;
    const int ct = t & 15, rt = t >> 4;
    float4 v[4];
    #pragma unroll
    for (int k = 0; k < 4; ++k)
        v[k] = *(const float4*)(src + sb + (long)(r0 + rt * 4 + k) * Cc + c0 + ct * 4);
    #pragma unroll
    for (int j = 0; j < 4; ++j) {
        ushort pk[4];
        #pragma unroll
        for (int k = 0; k < 4; ++k) pk[k] = f2bf(((const float*)&v[k])[j]);
        *(uint2*)&T[ct * 4 + j][rt * 4] = *(uint2*)pk;
    }
    __syncthreads();
    const int c = t >> 2, rq = (t & 3) * 16;
    ushort* d = dst + db + (long)(c0 + c) * R + r0 + rq;
    *(int4*)(d)     = *(const int4*)&T[c][rq];
    *(int4*)(d + 8) = *(const int4*)&T[c][rq + 8];
}

// ---------------------------------------------------------------------------
// Fused kv GEMM (bf16 MFMA) + phi + S = phi(K)^T V + k_sum (MFMA w/ ones).
// grid (s=16, h=8, b=4), 256 thr / 4 waves. Each WG: 8 subtiles of 128 tokens.
// HARDENED T3+T4 (this kernel ONLY — isolation experiment): dbuf gld_lds,
// counted vmcnt(8), builtin s_barrier, sched_barrier(0) fences, no unroll.
// ---------------------------------------------------------------------------
__global__ __launch_bounds__(256) void k_kv_s(
        const ushort* __restrict__ xt, const ushort* __restrict__ Wqt,
        const float* __restrict__ bqkv, float* __restrict__ S_g,
        float* __restrict__ ksum_g) {
    const int s = blockIdx.x, h = blockIdx.y, b = blockIdx.z;
    const int tid = threadIdx.x;
    const int w = tid >> 6, ln = tid & 63, lr = ln & 15, lq = ln >> 4;
    const int bh = b * H_ + h;
    const int lrow = ln >> 3;             // row-in-chunk 0..7
    const int csw  = (ln & 7) ^ lrow;     // pre-swizzled source col-chunk (16B units)
    const int sw   = lr & 7;              // fragment-read row swizzle

    __shared__ __align__(16) char smem[65536];
    ushort* A0 = (ushort*)smem;                   // [128][64] xor-swz
    ushort* B0 = (ushort*)(smem + 16384);
    ushort* A1 = (ushort*)(smem + 32768);
    ushort* B1 = (ushort*)(smem + 49152);
    ushort (*kvT)[PADT] = (ushort(*)[PADT])smem;  // epilogue alias, 34816B
    __shared__ float biasL[128];

    if (tid < 128) {
        int col = tid < 64 ? (512 + h * 64 + tid) : (1024 + h * 64 + (tid - 64));
        biasL[tid] = bqkv[col];
    }

    // per-lane invariant global element offsets for async staging
    int gA[4], gB[4];
    #pragma unroll
    for (int i = 0; i < 4; ++i) {
        const int row = (w * 4 + i) * 8 + lrow;
        gA[i] = row * C_ + csw * 8;
        const int wr = row < 64 ? (512 + h * 64 + row) : (1024 + h * 64 + (row - 64));
        gB[i] = wr * C_ + csw * 8;
    }
    const long xb = (long)b * N_ * C_;

    const f32x4 FZ = {0.f, 0.f, 0.f, 0.f};
    f32x4 Sacc[4] = {FZ, FZ, FZ, FZ};
    f32x4 Kacc = FZ;
    bf16x8 ONES;
    #pragma unroll
    for (int i = 0; i < 8; ++i) ONES[i] = (short)0x3F80;   // bf16 1.0

    __syncthreads();   // biasL visible; vmcnt clean before counted region

    for (int it = 0; it < 8; ++it) {
        const ushort* xa = xt + xb + (long)((s * 8 + it) * 128) * C_;
        f32x4 acc[2][8];
        #pragma unroll
        for (int mi = 0; mi < 2; mi++)
            #pragma unroll
            for (int ji = 0; ji < 8; ji++) acc[mi][ji] = FZ;

        auto stage = [&](ushort* Ab, ushort* Bb, int c0) {
            #pragma unroll
            for (int i = 0; i < 4; ++i) {
                const int ch = w * 4 + i;
                gld16(xa + gA[i] + c0, Ab + ch * 512);
                gld16(Wqt + gB[i] + c0, Bb + ch * 512);
            }
        };
        auto compute = [&](const ushort* Ab, const ushort* Bb) {
            #pragma unroll
            for (int ks = 0; ks < 2; ++ks) {
                const int cof = ((ks * 4 + lq) ^ sw) * 8;
                bf16x8 a[2], bb[8];
                #pragma unroll
                for (int mi = 0; mi < 2; mi++)
                    a[mi] = *(const bf16x8*)&Ab[(w * 32 + mi * 16 + lr) * 64 + cof];
                #pragma unroll
                for (int ji = 0; ji < 8; ji++)
                    bb[ji] = *(const bf16x8*)&Bb[(ji * 16 + lr) * 64 + cof];
                #pragma unroll
                for (int mi = 0; mi < 2; mi++)
                    #pragma unroll
                    for (int ji = 0; ji < 8; ji++)
                        acc[mi][ji] = __builtin_amdgcn_mfma_f32_16x16x32_bf16(
                            a[mi], bb[ji], acc[mi][ji], 0, 0, 0);
            }
        };

        stage(A0, B0, 0);                      // c0 in flight
        #pragma unroll 1
        for (int kc = 0; kc < 6; kc += 2) {    // steady state: c_kc..c_{kc+1}
            stage(A1, B1, (kc + 1) * 64);      // +8 -> 16 outstanding
            VMCNT(8); SCHED0();                // oldest 8 (c_kc) landed
            BAR(); SCHED0();                   // buf visible to all waves
            compute(A0, B0);
            SCHED0(); BAR(); SCHED0();         // readers done before overwrite
            stage(A0, B0, (kc + 2) * 64);
            VMCNT(8); SCHED0();                // c_{kc+1} landed
            BAR(); SCHED0();
            compute(A1, B1);
            SCHED0(); BAR(); SCHED0();
        }
        // tail: c6 (in A0), c7 (stage now into A1)
        stage(A1, B1, 7 * 64);
        VMCNT(8); SCHED0();                    // c6 landed
        BAR(); SCHED0();
        compute(A0, B0);
        SCHED0();
        VMCNT(0); SCHED0();                    // c7 landed (nothing else in flight)
        BAR(); SCHED0();
        compute(A1, B1);
        SCHED0();
        __syncthreads();                       // full fence before kvT alias reuse

        // epilogue: bias + phi(k) -> kvT (aliases A0/B0/low-A1)
        #pragma unroll
        for (int mi = 0; mi < 2; mi++) {
            int nl = w * 32 + mi * 16 + lq * 4;
            #pragma unroll
            for (int ji = 0; ji < 8; ji++) {
                int j = ji * 16 + lr;
                float bs = biasL[j];
                ushort pk[4];
                #pragma unroll
                for (int r = 0; r < 4; r++) {
                    float vv = acc[mi][ji][r] + bs;
                    if (j < 64) vv = phi_f(vv);
                    pk[r] = f2bf(vv);
                }
                *(uint2*)&kvT[j][nl] = *(uint2*)pk;
            }
        }
        __syncthreads();
        // S rank-update: wave w owns d-strip w*16..w*16+15; ksum via ones-MFMA
        #pragma unroll
        for (int ks = 0; ks < 4; ++ks) {
            bf16x8 af = *(const bf16x8*)&kvT[w * 16 + lr][ks * 32 + lq * 8];
            #pragma unroll
            for (int e = 0; e < 4; e++) {
                bf16x8 bv = *(const bf16x8*)&kvT[64 + e * 16 + lr][ks * 32 + lq * 8];
                Sacc[e] = __builtin_amdgcn_mfma_f32_16x16x32_bf16(af, bv, Sacc[e], 0, 0, 0);
            }
            Kacc = __builtin_amdgcn_mfma_f32_16x16x32_bf16(af, ONES, Kacc, 0, 0, 0);
        }
        __syncthreads();   // protect kvT from next it's prologue staging
    }
    #pragma unroll
    for (int e = 0; e < 4; e++)
        #pragma unroll
        for (int r = 0; r < 4; r++)
            atomicAdd(&S_g[((long)bh * 64 + w * 16 + lq * 4 + r) * 64 + e * 16 + lr],
                      Sacc[e][r]);
    if (lr == 0) {
        #pragma unroll
        for (int r = 0; r < 4; r++)
            atomicAdd(&ksum_g[bh * 64 + w * 16 + lq * 4 + r], Kacc[r]);
    }
}

// ---------------------------------------------------------------------------
// S finalize: SbT[bh][160][64] bf16 (hi rows 0..79, lo rows 80..159).
// ---------------------------------------------------------------------------
__global__ void k_sfin(const float* __restrict__ S_g, const float* __restrict__ ksum_g,
                       ushort* __restrict__ SbT) {
    int bh = blockIdx.x, t = threadIdx.x;
    for (int i = t; i < 5120; i += 256) {
        int e = i >> 6, d = i & 63;
        float v = (e < 64) ? S_g[(long)bh * 4096 + d * 64 + e]
                           : (e == 64 ? ksum_g[bh * 64 + d] : 0.f);
        ushort hi = f2bf(v);
        ushort lo = f2bf(v - bf2f(hi));
        SbT[(long)bh * 10240 + i] = hi;
        SbT[(long)bh * 10240 + 5120 + i] = lo;
    }
}

// ---------------------------------------------------------------------------
// Fused q GEMM + phi + num/den — ROUND-3 VERIFIED FORM (__syncthreads 2-phase).
// grid (ntile=128, h=8, b=4), 256 thr.
// ---------------------------------------------------------------------------
__global__ __launch_bounds__(256) void k_q_attn(
        const ushort* __restrict__ xt, const ushort* __restrict__ Wqt,
        const float* __restrict__ bqkv, const ushort* __restrict__ SbT,
        ushort* __restrict__ attn) {
    const int nt = blockIdx.x, h = blockIdx.y, b = blockIdx.z;
    const int n0 = nt * 128;
    const int tid = threadIdx.x;
    const int w = tid >> 6, ln = tid & 63, lr = ln & 15, lq = ln >> 4;
    const int bh = b * H_ + h;
    const int lrow = ln >> 3, csw = (ln & 7) ^ lrow, sw = lr & 7;

    __shared__ __align__(16) char smem[49152];
    ushort* A0 = (ushort*)smem;                 // [128][64] xor-swz; also phi(q)/attn
    ushort* A1 = (ushort*)(smem + 16384);
    ushort* Q0 = (ushort*)(smem + 32768);       // [64][64] xor-swz
    ushort* Q1 = (ushort*)(smem + 40960);
    __shared__ __align__(16) ushort Sb[160][PADA];
    __shared__ float denL[128];

    // stage S (hi+lo)
    #pragma unroll
    for (int p = 0; p < 5; ++p) {
        int r = p * 32 + (tid >> 3);
        *(int4*)&Sb[r][(tid & 7) * 8] =
            *(const int4*)(SbT + (long)bh * 10240 + r * 64 + (tid & 7) * 8);
    }

    int gA[4], gB[2];
    #pragma unroll
    for (int i = 0; i < 4; ++i) {
        const int row = (w * 4 + i) * 8 + lrow;
        gA[i] = (b * N_ + n0 + row) * C_ + csw * 8;
    }
    #pragma unroll
    for (int i = 0; i < 2; ++i) {
        const int j = (w * 2 + i) * 8 + lrow;
        gB[i] = (h * 64 + j) * C_ + csw * 8;
    }

    const f32x4 FZ = {0.f, 0.f, 0.f, 0.f};
    f32x4 accq[2][4];
    #pragma unroll
    for (int mi = 0; mi < 2; mi++)
        #pragma unroll
        for (int ji = 0; ji < 4; ji++) accq[mi][ji] = FZ;

    auto stage = [&](ushort* Ab, ushort* Bb, int c0) {
        #pragma unroll
        for (int i = 0; i < 4; ++i)
            gld16(xt + gA[i] + c0, Ab + (w * 4 + i) * 512);
        #pragma unroll
        for (int i = 0; i < 2; ++i)
            gld16(Wqt + gB[i] + c0, Bb + (w * 2 + i) * 512);
    };
    auto compute = [&](const ushort* Ab, const ushort* Bb) {
        #pragma unroll
        for (int ks = 0; ks < 2; ++ks) {
            const int cof = ((ks * 4 + lq) ^ sw) * 8;
            bf16x8 a[2], bb[4];
            #pragma unroll
            for (int mi = 0; mi < 2; mi++)
                a[mi] = *(const bf16x8*)&Ab[(w * 32 + mi * 16 + lr) * 64 + cof];
            #pragma unroll
            for (int ji = 0; ji < 4; ji++)
                bb[ji] = *(const bf16x8*)&Bb[(ji * 16 + lr) * 64 + cof];
            #pragma unroll
            for (int mi = 0; mi < 2; mi++)
                #pragma unroll
                for (int ji = 0; ji < 4; ji++)
                    accq[mi][ji] = __builtin_amdgcn_mfma_f32_16x16x32_bf16(
                        a[mi], bb[ji], accq[mi][ji], 0, 0, 0);
        }
    };

    stage(A0, Q0, 0);
    __syncthreads();
    #pragma unroll
    for (int kc = 0; kc < 8; kc += 2) {
        stage(A1, Q1, (kc + 1) * 64);
        compute(A0, Q0);
        __syncthreads();
        if (kc + 2 < 8) stage(A0, Q0, (kc + 2) * 64);
        compute(A1, Q1);
        __syncthreads();
    }
    // phi(q) -> A0[n][d] (swizzled scalar writes, wave-private rows)
    #pragma unroll
    for (int mi = 0; mi < 2; mi++) {
        int nl = w * 32 + mi * 16 + lq * 4;
        #pragma unroll
        for (int ji = 0; ji < 4; ji++) {
            int d = ji * 16 + lr;
            float bs = bqkv[h * 64 + d];
            #pragma unroll
            for (int r = 0; r < 4; r++) {
                int row = nl + r;
                A0[row * 64 + ((((d >> 3) ^ (row & 7)) << 3) | (d & 7))] =
                    f2bf(phi_f(accq[mi][ji][r] + bs));
            }
        }
    }
    __syncthreads();
    // num (+den col 64) MFMA, hi+lo
    f32x4 accn[2][5];
    #pragma unroll
    for (int mi = 0; mi < 2; mi++)
        #pragma unroll
        for (int ei = 0; ei < 5; ei++) accn[mi][ei] = FZ;
    #pragma unroll
    for (int ks = 0; ks < 2; ++ks) {
        const int cof = ((ks * 4 + lq) ^ sw) * 8;
        bf16x8 a[2];
        #pragma unroll
        for (int mi = 0; mi < 2; mi++)
            a[mi] = *(const bf16x8*)&A0[(w * 32 + mi * 16 + lr) * 64 + cof];
        #pragma unroll
        for (int ei = 0; ei < 5; ei++) {
            bf16x8 bhi = *(const bf16x8*)&Sb[ei * 16 + lr][ks * 32 + lq * 8];
            bf16x8 blo = *(const bf16x8*)&Sb[80 + ei * 16 + lr][ks * 32 + lq * 8];
            #pragma unroll
            for (int mi = 0; mi < 2; mi++) {
                accn[mi][ei] = __builtin_amdgcn_mfma_f32_16x16x32_bf16(
                    a[mi], bhi, accn[mi][ei], 0, 0, 0);
                accn[mi][ei] = __builtin_amdgcn_mfma_f32_16x16x32_bf16(
                    a[mi], blo, accn[mi][ei], 0, 0, 0);
            }
        }
    }
    if (lr == 0) {
        #pragma unroll
        for (int mi = 0; mi < 2; mi++)
            #pragma unroll
            for (int r = 0; r < 4; r++)
                denL[w * 32 + mi * 16 + lq * 4 + r] = accn[mi][4][r] + EPS;
    }
    __syncthreads();
    // attn = num/den -> A0 (swizzled)
    #pragma unroll
    for (int mi = 0; mi < 2; mi++) {
        int nl = w * 32 + mi * 16 + lq * 4;
        #pragma unroll
        for (int ji = 0; ji < 4; ji++) {
            int e = ji * 16 + lr;
            #pragma unroll
            for (int r = 0; r < 4; r++) {
                int row = nl + r;
                A0[row * 64 + ((((e >> 3) ^ (row & 7)) << 3) | (e & 7))] =
                    f2bf(accn[mi][ji][r] / denL[row]);
            }
        }
    }
    __syncthreads();
    // coalesced store: attn ws [b][n][h*64 .. h*64+64)  (un-swizzle on read)
    {
        int row = tid >> 1, co = (tid & 1) * 32;
        int4* dp = (int4*)(attn + ((long)(b * N_ + n0 + row)) * C_ + h * 64 + co);
        #pragma unroll
        for (int k = 0; k < 4; ++k)
            dp[k] = *(const int4*)&A0[row * 64 + ((((co >> 3) + k) ^ (row & 7)) << 3)];
    }
}

// ---------------------------------------------------------------------------
// Proj GEMM — ROUND-3 VERIFIED FORM (__syncthreads 2-phase dbuf).
// grid (nt=512, jt=4), 128x128 tile, LDS-transposed coalesced f32 store.
// ---------------------------------------------------------------------------
__global__ __launch_bounds__(256) void k_proj(
        const ushort* __restrict__ attn, const ushort* __restrict__ Wpt,
        const float* __restrict__ bproj, float* __restrict__ out) {
    const int nt = blockIdx.x, jt = blockIdx.y;
    const int tid = threadIdx.x;
    const int w = tid >> 6, ln = tid & 63, lr = ln & 15, lq = ln >> 4;
    const int b = nt >> 7;
    const int nloc = (nt & 127) * 128;
    const int lrow = ln >> 3, csw = (ln & 7) ^ lrow, sw = lr & 7;

    __shared__ __align__(16) char smem[65536];
    ushort* A0 = (ushort*)smem;
    ushort* B0 = (ushort*)(smem + 16384);
    ushort* A1 = (ushort*)(smem + 32768);
    ushort* B1 = (ushort*)(smem + 49152);
    float (*outT)[PADO] = (float(*)[PADO])smem;  // 64x132x4 = 33792 alias

    int gA[4], gB[4];
    #pragma unroll
    for (int i = 0; i < 4; ++i) {
        const int row = (w * 4 + i) * 8 + lrow;
        gA[i] = (nt * 128 + row) * C_ + csw * 8;
        gB[i] = (jt * 128 + row) * C_ + csw * 8;
    }

    const f32x4 FZ = {0.f, 0.f, 0.f, 0.f};
    f32x4 acc[2][8];
    #pragma unroll
    for (int mi = 0; mi < 2; mi++)
        #pragma unroll
        for (int ji = 0; ji < 8; ji++) acc[mi][ji] = FZ;

    auto stage = [&](ushort* Ab, ushort* Bb, int c0) {
        #pragma unroll
        for (int i = 0; i < 4; ++i) {
            const int ch = w * 4 + i;
            gld16(attn + gA[i] + c0, Ab + ch * 512);
            gld16(Wpt + gB[i] + c0, Bb + ch * 512);
        }
    };
    auto compute = [&](const ushort* Ab, const ushort* Bb) {
        #pragma unroll
        for (int ks = 0; ks < 2; ++ks) {
            const int cof = ((ks * 4 + lq) ^ sw) * 8;
            bf16x8 a[2], bb[8];
            #pragma unroll
            for (int mi = 0; mi < 2; mi++)
                a[mi] = *(const bf16x8*)&Ab[(w * 32 + mi * 16 + lr) * 64 + cof];
            #pragma unroll
            for (int ji = 0; ji < 8; ji++)
                bb[ji] = *(const bf16x8*)&Bb[(ji * 16 + lr) * 64 + cof];
            #pragma unroll
            for (int mi = 0; mi < 2; mi++)
                #pragma unroll
                for (int ji = 0; ji < 8; ji++)
                    acc[mi][ji] = __builtin_amdgcn_mfma_f32_16x16x32_bf16(
                        a[mi], bb[ji], acc[mi][ji], 0, 0, 0);
        }
    };

    stage(A0, B0, 0);
    __syncthreads();
    #pragma unroll
    for (int kc = 0; kc < 8; kc += 2) {
        stage(A1, B1, (kc + 1) * 64);
        compute(A0, B0);
        __syncthreads();
        if (kc + 2 < 8) stage(A0, B0, (kc + 2) * 64);
        compute(A1, B1);
        __syncthreads();
    }
    #pragma unroll
    for (int half = 0; half < 2; ++half) {
        if (half) __syncthreads();
        #pragma unroll
        for (int mi = 0; mi < 2; mi++) {
            int nl = w * 32 + mi * 16 + lq * 4;
            #pragma unroll
            for (int ji = 0; ji < 4; ji++) {
                int cl = ji * 16 + lr;
                float bs = bproj[jt * 128 + half * 64 + cl];
                f32x4 v = acc[mi][half * 4 + ji];
                #pragma unroll
                for (int r = 0; r < 4; r++) v[r] += bs;
                *(f32x4*)&outT[cl][nl] = v;     // ds_write_b128
            }
        }
        __syncthreads();
        {
            int cl = tid >> 2, ch = (tid & 3) * 32;
            const float* sp = &outT[cl][ch];
            float* dp = out + ((long)(b * C_ + jt * 128 + half * 64 + cl)) * N_ + nloc + ch;
            #pragma unroll
            for (int k = 0; k < 8; ++k)
                ((float4*)dp)[k] = ((const float4*)sp)[k];
        }
    }
}

// ===========================================================================
// Round-1 fp32 fallback (used only if ws_size is too small for the MFMA path)
// ===========================================================================
__global__ __launch_bounds__(256) void kernelA_fb(
        const float* __restrict__ x, const float* __restrict__ Wqkv,
        const float* __restrict__ bqkv, float* __restrict__ S_g,
        float* __restrict__ ksum_g) {
    const int h = blockIdx.x;
    const int s = blockIdx.y;
    const int b = blockIdx.z;
    const int tid = threadIdx.x;
    const int tn = tid & 15;
    const int tj = tid >> 4;
    const int td = tid & 15;
    const int te = tid >> 4;

    __shared__ float As[16][64];
    __shared__ float Bs[16][128];
    __shared__ float kphi_s[64][64];
    __shared__ float v_s[64][64];

    float acc2[4][4];
    #pragma unroll
    for (int i = 0; i < 4; i++)
        #pragma unroll
        for (int j = 0; j < 4; j++) acc2[i][j] = 0.f;
    float ksum_r = 0.f;

    float bias_j[8];
    #pragma unroll
    for (int jj = 0; jj < 8; jj++) {
        int j = tj * 8 + jj;
        int col = (j < 64) ? (512 + h * 64 + j) : (1024 + h * 64 + (j - 64));
        bias_j[jj] = bqkv[col];
    }

    for (int it = 0; it < 8; ++it) {
        const int n0 = (s * 8 + it) * 64;
        float acc[4][8];
        #pragma unroll
        for (int i = 0; i < 4; i++)
            #pragma unroll
            for (int jj = 0; jj < 8; jj++) acc[i][jj] = 0.f;

        for (int kc = 0; kc < 32; ++kc) {
            const int c0 = kc * 16;
            __syncthreads();
            {
                int r = tid >> 4, n4 = (tid & 15) * 4;
                const float* src = x + ((size_t)b * C_ + (c0 + r)) * (size_t)N_ + n0 + n4;
                *(float4*)&As[r][n4] = *(const float4*)src;
            }
            #pragma unroll
            for (int part = 0; part < 2; ++part) {
                int idx = tid + part * 256;
                int r = idx >> 5;
                int j4 = (idx & 31) * 4;
                int col = (j4 < 64) ? (512 + h * 64 + j4) : (1024 + h * 64 + (j4 - 64));
                const float* src = Wqkv + (size_t)(c0 + r) * C3_ + col;
                *(float4*)&Bs[r][j4] = *(const float4*)src;
            }
            __syncthreads();
            #pragma unroll
            for (int k = 0; k < 16; ++k) {
                float a[4], bb[8];
                *(float4*)a      = *(const float4*)&As[k][tn * 4];
                *(float4*)&bb[0] = *(const float4*)&Bs[k][tj * 8];
                *(float4*)&bb[4] = *(const float4*)&Bs[k][tj * 8 + 4];
                #pragma unroll
                for (int i = 0; i < 4; i++)
                    #pragma unroll
                    for (int jj = 0; jj < 8; jj++)
                        acc[i][jj] = fmaf(a[i], bb[jj], acc[i][jj]);
            }
        }
        __syncthreads();
        if (tj < 8) {
            #pragma unroll
            for (int i = 0; i < 4; i++) {
                int n = tn * 4 + i;
                float tmp[8];
                #pragma unroll
                for (int jj = 0; jj < 8; jj++) tmp[jj] = phi_f(acc[i][jj] + bias_j[jj]);
                *(float4*)&kphi_s[n][tj * 8]     = *(float4*)&tmp[0];
                *(float4*)&kphi_s[n][tj * 8 + 4] = *(float4*)&tmp[4];
            }
        } else {
            #pragma unroll
            for (int i = 0; i < 4; i++) {
                int n = tn * 4 + i;
                float tmp[8];
                #pragma unroll
                for (int jj = 0; jj < 8; jj++) tmp[jj] = acc[i][jj] + bias_j[jj];
                *(float4*)&v_s[n][(tj - 8) * 8]     = *(float4*)&tmp[0];
                *(float4*)&v_s[n][(tj - 8) * 8 + 4] = *(float4*)&tmp[4];
            }
        }
        __syncthreads();
        #pragma unroll 4
        for (int n = 0; n < 64; ++n) {
            float a[4], bb[4];
            *(float4*)a  = *(const float4*)&kphi_s[n][td * 4];
            *(float4*)bb = *(const float4*)&v_s[n][te * 4];
            #pragma unroll
            for (int dd = 0; dd < 4; dd++)
                #pragma unroll
                for (int ee = 0; ee < 4; ee++)
                    acc2[dd][ee] = fmaf(a[dd], bb[ee], acc2[dd][ee]);
        }
        if (tid < 64) {
            float sum = 0.f;
            #pragma unroll 8
            for (int n = 0; n < 64; ++n) sum += kphi_s[n][tid];
            ksum_r += sum;
        }
    }

    const int bh = b * H_ + h;
    #pragma unroll
    for (int dd = 0; dd < 4; dd++)
        #pragma unroll
        for (int ee = 0; ee < 4; ee++)
            atomicAdd(&S_g[((size_t)bh * 64 + td * 4 + dd) * 64 + te * 4 + ee], acc2[dd][ee]);
    if (tid < 64) atomicAdd(&ksum_g[bh * 64 + tid], ksum_r);
}

__global__ __launch_bounds__(256) void kernelB_fb(
        const float* __restrict__ x, const float* __restrict__ Wqkv,
        const float* __restrict__ bqkv, const float* __restrict__ Wproj,
        const float* __restrict__ bproj, const float* __restrict__ S_g,
        const float* __restrict__ ksum_g, float* __restrict__ out) {
    const int nt = blockIdx.x;
    const int b  = blockIdx.y;
    const int n0 = nt * 16;
    const int tid = threadIdx.x;
    const int tn = tid & 3;
    const int tj = tid >> 2;

    __shared__ float QA[512][16];
    __shared__ float As[16][16];
    __shared__ float Bs2[16][256];
    __shared__ float SB[16][64];
    __shared__ float ksumL[512];
    __shared__ float denL[16];

    ksumL[tid]       = ksum_g[(size_t)b * 512 + tid];
    ksumL[tid + 256] = ksum_g[(size_t)b * 512 + tid + 256];

    for (int half = 0; half < 2; ++half) {
        float acc[4][4];
        #pragma unroll
        for (int i = 0; i < 4; i++)
            #pragma unroll
            for (int j = 0; j < 4; j++) acc[i][j] = 0.f;

        for (int kc = 0; kc < 32; ++kc) {
            const int c0 = kc * 16;
            __syncthreads();
            {
                int r = tid >> 4, n = tid & 15;
                As[r][n] = x[((size_t)b * C_ + c0 + r) * (size_t)N_ + n0 + n];
            }
            {
                int r = tid >> 4;
                int j0 = (tid & 15) * 16;
                const float* src = Wqkv + (size_t)(c0 + r) * C3_ + half * 256 + j0;
                float4* dst = (float4*)&Bs2[r][j0];
                #pragma unroll
                for (int q4 = 0; q4 < 4; q4++) dst[q4] = ((const float4*)src)[q4];
            }
            __syncthreads();
            #pragma unroll
            for (int k = 0; k < 16; ++k) {
                float a[4], bb[4];
                *(float4*)a  = *(const float4*)&As[k][tn * 4];
                *(float4*)bb = *(const float4*)&Bs2[k][tj * 4];
                #pragma unroll
                for (int i = 0; i < 4; i++)
                    #pragma unroll
                    for (int jj = 0; jj < 4; jj++)
                        acc[i][jj] = fmaf(a[i], bb[jj], acc[i][jj]);
            }
        }
        #pragma unroll
        for (int jj = 0; jj < 4; jj++) {
            int c = half * 256 + tj * 4 + jj;
            float bq = bqkv[c];
            float tmp[4];
            #pragma unroll
            for (int i = 0; i < 4; i++) tmp[i] = phi_f(acc[i][jj] + bq);
            *(float4*)&QA[c][tn * 4] = *(float4*)tmp;
        }
    }
    __syncthreads();

    for (int h = 0; h < H_; ++h) {
        if (tid < 16) {
            float d = 0.f;
            #pragma unroll 8
            for (int dd = 0; dd < 64; ++dd)
                d = fmaf(QA[h * 64 + dd][tid], ksumL[h * 64 + dd], d);
            denL[tid] = d + EPS;
        }
        float acc4[4] = {0.f, 0.f, 0.f, 0.f};
        for (int dc = 0; dc < 4; ++dc) {
            __syncthreads();
            {
                int r = tid >> 4, e4 = (tid & 15) * 4;
                *(float4*)&SB[r][e4] =
                    *(const float4*)&S_g[(((size_t)(b * H_ + h)) * 64 + dc * 16 + r) * 64 + e4];
            }
            __syncthreads();
            #pragma unroll
            for (int k = 0; k < 16; ++k) {
                float a[4];
                *(float4*)a = *(const float4*)&QA[h * 64 + dc * 16 + k][tn * 4];
                float bb = SB[k][tj];
                #pragma unroll
                for (int i = 0; i < 4; i++) acc4[i] = fmaf(a[i], bb, acc4[i]);
            }
        }
        __syncthreads();
        {
            float tmp[4];
            #pragma unroll
            for (int i = 0; i < 4; i++) tmp[i] = acc4[i] / denL[tn * 4 + i];
            *(float4*)&QA[h * 64 + tj][tn * 4] = *(float4*)tmp;
        }
        __syncthreads();
    }

    for (int half = 0; half < 2; ++half) {
        float acc[4][4];
        #pragma unroll
        for (int i = 0; i < 4; i++)
            #pragma unroll
            for (int j = 0; j < 4; j++) acc[i][j] = 0.f;

        for (int kc = 0; kc < 32; ++kc) {
            __syncthreads();
            {
                int r = tid >> 4;
                int j0 = (tid & 15) * 16;
                const float* src = Wproj + (size_t)(kc * 16 + r) * C_ + half * 256 + j0;
                float4* dst = (float4*)&Bs2[r][j0];
                #pragma unroll
                for (int q4 = 0; q4 < 4; q4++) dst[q4] = ((const float4*)src)[q4];
            }
            __syncthreads();
            #pragma unroll
            for (int k = 0; k < 16; ++k) {
                float a[4], bb[4];
                *(float4*)a  = *(const float4*)&QA[kc * 16 + k][tn * 4];
                *(float4*)bb = *(const float4*)&Bs2[k][tj * 4];
                #pragma unroll
                for (int i = 0; i < 4; i++)
                    #pragma unroll
                    for (int jj = 0; jj < 4; jj++)
                        acc[i][jj] = fmaf(a[i], bb[jj], acc[i][jj]);
            }
        }
        #pragma unroll
        for (int jj = 0; jj < 4; jj++) {
            int c = half * 256 + tj * 4 + jj;
            float bp = bproj[c];
            float tmp[4];
            #pragma unroll
            for (int i = 0; i < 4; i++) tmp[i] = acc[i][jj] + bp;
            *(float4*)&out[((size_t)b * C_ + c) * (size_t)N_ + n0 + tn * 4] = *(float4*)tmp;
        }
    }
}

// ===========================================================================
extern "C" void kernel_launch(void* const* d_in, const int* in_sizes, int n_in,
                              void* d_out, int out_size, void* d_ws, size_t ws_size,
                              hipStream_t stream) {
    const float* x     = (const float*)d_in[0];
    const float* Wqkv  = (const float*)d_in[1];
    const float* bqkv  = (const float*)d_in[2];
    const float* Wproj = (const float*)d_in[3];
    const float* bproj = (const float*)d_in[4];
    float* out = (float*)d_out;

    // ---- workspace layout (bytes) ----
    const size_t oS    = 0;                        // S_g f32 [32][64][64]   524288
    const size_t oK    = oS + 524288;              // ksum f32 [32][64]      8192
    const size_t oXT   = oK + 8192;                // xt bf16 [4][16384][512] 67108864
    const size_t oWq   = oXT + 67108864;           // Wq_t bf16 [1536][512]  1572864
    const size_t oWp   = oWq + 1572864;            // Wp_t bf16 [512][512]   524288
    const size_t oSbT  = oWp + 524288;             // SbT bf16 [32][160][64] 655360
    const size_t oAttn = oSbT + 655360;            // attn bf16 [4][16384][512] 67108864
    const size_t need  = oAttn + 67108864;         // = 137,502,720

    float* S_g    = (float*)((char*)d_ws + oS);
    float* ksum_g = (float*)((char*)d_ws + oK);

    if (ws_size < need) {
        // fp32 fallback (round-1 path)
        hipMemsetAsync(d_ws, 0, 532480, stream);
        kernelA_fb<<<dim3(H_, 32, B_), 256, 0, stream>>>(x, Wqkv, bqkv, S_g, ksum_g);
        kernelB_fb<<<dim3(N_ / 16, B_), 256, 0, stream>>>(x, Wqkv, bqkv, Wproj, bproj,
                                                          S_g, ksum_g, out);
        return;
    }

    ushort* xt   = (ushort*)((char*)d_ws + oXT);
    ushort* Wqt  = (ushort*)((char*)d_ws + oWq);
    ushort* Wpt  = (ushort*)((char*)d_ws + oWp);
    ushort* SbT  = (ushort*)((char*)d_ws + oSbT);
    ushort* attn = (ushort*)((char*)d_ws + oAttn);

    hipMemsetAsync(d_ws, 0, 532480, stream);  // S_g + ksum
    k_transpose<<<dim3(N_ / 64, C_ / 64, B_), 256, 0, stream>>>(
        x, xt, C_, N_, (long)C_ * N_, (long)N_ * C_);
    k_transpose<<<dim3(C3_ / 64, C_ / 64, 1), 256, 0, stream>>>(
        Wqkv, Wqt, C_, C3_, 0, 0);
    k_transpose<<<dim3(C_ / 64, C_ / 64, 1), 256, 0, stream>>>(
        Wproj, Wpt, C_, C_, 0, 0);
    k_kv_s<<<dim3(16, H_, B_), 256, 0, stream>>>(xt, Wqt, bqkv, S_g, ksum_g);
    k_sfin<<<dim3(B_ * H_), 256, 0, stream>>>(S_g, ksum_g, SbT);
    k_q_attn<<<dim3(N_ / 128, H_, B_), 256, 0, stream>>>(xt, Wqt, bqkv, SbT, attn);
    k_proj<<<dim3((B_ * N_) / 128, 4), 256, 0, stream>>>(attn, Wpt, bproj, out);
}

// Round 7
// 510.013 us; speedup vs baseline: 1.0255x; 1.0255x over previous
//
#include <hip/hip_runtime.h>
#include <cmath>

#define B_  4
#define C_  512
#define N_  16384
#define H_  8
#define D_  64
#define C3_ 1536
#define EPS 1e-6f

#define PADA 72    // bf16 tile leading pad (Sb in k_q_attn, transpose tiles)
#define PADT 136   // [j][n] transposed kv tile pad
#define PADO 132   // f32 out-transpose pad

typedef __attribute__((ext_vector_type(8))) short bf16x8;
typedef __attribute__((ext_vector_type(4))) float f32x4;

typedef const void __attribute__((address_space(1)))* gas_t;
typedef void __attribute__((address_space(3)))* las_t;

// async direct-to-LDS copy: wave-uniform LDS base, per-lane global src, 16B/lane.
__device__ __forceinline__ void gld16(const void* g, void* l) {
    __builtin_amdgcn_global_load_lds((gas_t)(unsigned long long)g,
                                     (las_t)(unsigned)(unsigned long long)l,
                                     16, 0, 0);
}

// counted vmem wait (T4): leave N newest loads in flight. Literal N only.
// Rule #18: every VMCNT/BARRIER followed by sched_barrier(0) — hipcc can move
// instructions past inline-asm waitcnt despite the "memory" clobber.
// VERIFIED round 6 on k_kv_s: 136->126us, bit-exact.
#define VMCNT(N) asm volatile("s_waitcnt vmcnt(" #N ")" ::: "memory")
#define SCHED0() __builtin_amdgcn_sched_barrier(0)
#define BAR()    __builtin_amdgcn_s_barrier()

__device__ __forceinline__ ushort f2bf(float f) {
    union { float f; unsigned u; } c{f};
    unsigned r = (c.u + 0x7FFF + ((c.u >> 16) & 1)) >> 16;  // RNE
    return (ushort)r;
}
__device__ __forceinline__ float bf2f(ushort b) {
    union { unsigned u; float f; } c{(unsigned)b << 16};
    return c.f;
}
__device__ __forceinline__ float phi_f(float x) { return x > 0.f ? x + 1.f : __expf(x); }

// ---------------------------------------------------------------------------
// Generic transpose+cast: src f32 [R][Cc] -> dst bf16 [Cc][R].  Tiles 64x64.
// ---------------------------------------------------------------------------
__global__ __launch_bounds__(256) void k_transpose(
        const float* __restrict__ src, ushort* __restrict__ dst,
        int R, int Cc, long sStride, long dStride) {
    __shared__ ushort T[64][72];
    const long sb = (long)blockIdx.z * sStride;
    const long db = (long)blockIdx.z * dStride;
    const int c0 = blockIdx.x * 64, r0 = blockIdx.y * 64;
    const int t = threadIdx.x;
    const int ct = t & 15, rt = t >> 4;
    float4 v[4];
    #pragma unroll
    for (int k = 0; k < 4; ++k)
        v[k] = *(const float4*)(src + sb + (long)(r0 + rt * 4 + k) * Cc + c0 + ct * 4);
    #pragma unroll
    for (int j = 0; j < 4; ++j) {
        ushort pk[4];
        #pragma unroll
        for (int k = 0; k < 4; ++k) pk[k] = f2bf(((const float*)&v[k])[j]);
        *(uint2*)&T[ct * 4 + j][rt * 4] = *(uint2*)pk;
    }
    __syncthreads();
    const int c = t >> 2, rq = (t & 3) * 16;
    ushort* d = dst + db + (long)(c0 + c) * R + r0 + rq;
    *(int4*)(d)     = *(const int4*)&T[c][rq];
    *(int4*)(d + 8) = *(const int4*)&T[c][rq + 8];
}

// ---------------------------------------------------------------------------
// Fused kv GEMM (bf16 MFMA) + phi + S = phi(K)^T V + k_sum (MFMA w/ ones).
// grid (s=16, h=8, b=4), 256 thr / 4 waves. Each WG: 8 subtiles of 128 tokens.
// HARDENED T3+T4 (verified r6) + T5 setprio A/B this round.
// ---------------------------------------------------------------------------
__global__ __launch_bounds__(256) void k_kv_s(
        const ushort* __restrict__ xt, const ushort* __restrict__ Wqt,
        const float* __restrict__ bqkv, float* __restrict__ S_g,
        float* __restrict__ ksum_g) {
    const int s = blockIdx.x, h = blockIdx.y, b = blockIdx.z;
    const int tid = threadIdx.x;
    const int w = tid >> 6, ln = tid & 63, lr = ln & 15, lq = ln >> 4;
    const int bh = b * H_ + h;
    const int lrow = ln >> 3;             // row-in-chunk 0..7
    const int csw  = (ln & 7) ^ lrow;     // pre-swizzled source col-chunk (16B units)
    const int sw   = lr & 7;              // fragment-read row swizzle

    __shared__ __align__(16) char smem[65536];
    ushort* A0 = (ushort*)smem;                   // [128][64] xor-swz
    ushort* B0 = (ushort*)(smem + 16384);
    ushort* A1 = (ushort*)(smem + 32768);
    ushort* B1 = (ushort*)(smem + 49152);
    ushort (*kvT)[PADT] = (ushort(*)[PADT])smem;  // epilogue alias, 34816B
    __shared__ float biasL[128];

    if (tid < 128) {
        int col = tid < 64 ? (512 + h * 64 + tid) : (1024 + h * 64 + (tid - 64));
        biasL[tid] = bqkv[col];
    }

    // per-lane invariant global element offsets for async staging
    int gA[4], gB[4];
    #pragma unroll
    for (int i = 0; i < 4; ++i) {
        const int row = (w * 4 + i) * 8 + lrow;
        gA[i] = row * C_ + csw * 8;
        const int wr = row < 64 ? (512 + h * 64 + row) : (1024 + h * 64 + (row - 64));
        gB[i] = wr * C_ + csw * 8;
    }
    const long xb = (long)b * N_ * C_;

    const f32x4 FZ = {0.f, 0.f, 0.f, 0.f};
    f32x4 Sacc[4] = {FZ, FZ, FZ, FZ};
    f32x4 Kacc = FZ;
    bf16x8 ONES;
    #pragma unroll
    for (int i = 0; i < 8; ++i) ONES[i] = (short)0x3F80;   // bf16 1.0

    __syncthreads();   // biasL visible; vmcnt clean before counted region

    for (int it = 0; it < 8; ++it) {
        const ushort* xa = xt + xb + (long)((s * 8 + it) * 128) * C_;
        f32x4 acc[2][8];
        #pragma unroll
        for (int mi = 0; mi < 2; mi++)
            #pragma unroll
            for (int ji = 0; ji < 8; ji++) acc[mi][ji] = FZ;

        auto stage = [&](ushort* Ab, ushort* Bb, int c0) {
            #pragma unroll
            for (int i = 0; i < 4; ++i) {
                const int ch = w * 4 + i;
                gld16(xa + gA[i] + c0, Ab + ch * 512);
                gld16(Wqt + gB[i] + c0, Bb + ch * 512);
            }
        };
        auto compute = [&](const ushort* Ab, const ushort* Bb) {
            #pragma unroll
            for (int ks = 0; ks < 2; ++ks) {
                const int cof = ((ks * 4 + lq) ^ sw) * 8;
                bf16x8 a[2], bb[8];
                #pragma unroll
                for (int mi = 0; mi < 2; mi++)
                    a[mi] = *(const bf16x8*)&Ab[(w * 32 + mi * 16 + lr) * 64 + cof];
                #pragma unroll
                for (int ji = 0; ji < 8; ji++)
                    bb[ji] = *(const bf16x8*)&Bb[(ji * 16 + lr) * 64 + cof];
                __builtin_amdgcn_s_setprio(1);           // T5 A/B (this kernel only)
                #pragma unroll
                for (int mi = 0; mi < 2; mi++)
                    #pragma unroll
                    for (int ji = 0; ji < 8; ji++)
                        acc[mi][ji] = __builtin_amdgcn_mfma_f32_16x16x32_bf16(
                            a[mi], bb[ji], acc[mi][ji], 0, 0, 0);
                __builtin_amdgcn_s_setprio(0);
            }
        };

        stage(A0, B0, 0);                      // c0 in flight
        #pragma unroll 1
        for (int kc = 0; kc < 6; kc += 2) {    // steady state: c_kc..c_{kc+1}
            stage(A1, B1, (kc + 1) * 64);      // +8 -> 16 outstanding
            VMCNT(8); SCHED0();                // oldest 8 (c_kc) landed
            BAR(); SCHED0();                   // buf visible to all waves
            compute(A0, B0);
            SCHED0(); BAR(); SCHED0();         // readers done before overwrite
            stage(A0, B0, (kc + 2) * 64);
            VMCNT(8); SCHED0();                // c_{kc+1} landed
            BAR(); SCHED0();
            compute(A1, B1);
            SCHED0(); BAR(); SCHED0();
        }
        // tail: c6 (in A0), c7 (stage now into A1)
        stage(A1, B1, 7 * 64);
        VMCNT(8); SCHED0();                    // c6 landed
        BAR(); SCHED0();
        compute(A0, B0);
        SCHED0();
        VMCNT(0); SCHED0();                    // c7 landed (nothing else in flight)
        BAR(); SCHED0();
        compute(A1, B1);
        SCHED0();
        __syncthreads();                       // full fence before kvT alias reuse

        // epilogue: bias + phi(k) -> kvT (aliases A0/B0/low-A1)
        #pragma unroll
        for (int mi = 0; mi < 2; mi++) {
            int nl = w * 32 + mi * 16 + lq * 4;
            #pragma unroll
            for (int ji = 0; ji < 8; ji++) {
                int j = ji * 16 + lr;
                float bs = biasL[j];
                ushort pk[4];
                #pragma unroll
                for (int r = 0; r < 4; r++) {
                    float vv = acc[mi][ji][r] + bs;
                    if (j < 64) vv = phi_f(vv);
                    pk[r] = f2bf(vv);
                }
                *(uint2*)&kvT[j][nl] = *(uint2*)pk;
            }
        }
        __syncthreads();
        // S rank-update: wave w owns d-strip w*16..w*16+15; ksum via ones-MFMA
        #pragma unroll
        for (int ks = 0; ks < 4; ++ks) {
            bf16x8 af = *(const bf16x8*)&kvT[w * 16 + lr][ks * 32 + lq * 8];
            #pragma unroll
            for (int e = 0; e < 4; e++) {
                bf16x8 bv = *(const bf16x8*)&kvT[64 + e * 16 + lr][ks * 32 + lq * 8];
                Sacc[e] = __builtin_amdgcn_mfma_f32_16x16x32_bf16(af, bv, Sacc[e], 0, 0, 0);
            }
            Kacc = __builtin_amdgcn_mfma_f32_16x16x32_bf16(af, ONES, Kacc, 0, 0, 0);
        }
        __syncthreads();   // protect kvT from next it's prologue staging
    }
    #pragma unroll
    for (int e = 0; e < 4; e++)
        #pragma unroll
        for (int r = 0; r < 4; r++)
            atomicAdd(&S_g[((long)bh * 64 + w * 16 + lq * 4 + r) * 64 + e * 16 + lr],
                      Sacc[e][r]);
    if (lr == 0) {
        #pragma unroll
        for (int r = 0; r < 4; r++)
            atomicAdd(&ksum_g[bh * 64 + w * 16 + lq * 4 + r], Kacc[r]);
    }
}

// ---------------------------------------------------------------------------
// S finalize: SbT[bh][160][64] bf16 (hi rows 0..79, lo rows 80..159).
// ---------------------------------------------------------------------------
__global__ void k_sfin(const float* __restrict__ S_g, const float* __restrict__ ksum_g,
                       ushort* __restrict__ SbT) {
    int bh = blockIdx.x, t = threadIdx.x;
    for (int i = t; i < 5120; i += 256) {
        int e = i >> 6, d = i & 63;
        float v = (e < 64) ? S_g[(long)bh * 4096 + d * 64 + e]
                           : (e == 64 ? ksum_g[bh * 64 + d] : 0.f);
        ushort hi = f2bf(v);
        ushort lo = f2bf(v - bf2f(hi));
        SbT[(long)bh * 10240 + i] = hi;
        SbT[(long)bh * 10240 + 5120 + i] = lo;
    }
}

// ---------------------------------------------------------------------------
// Fused q GEMM + phi + num/den (MFMA, ksum col 64, hi+lo S) + attn store.
// grid (ntile=128, h=8, b=4), 256 thr.  HARDENED T3+T4 (r6 recipe, VMCNT(6)).
// ---------------------------------------------------------------------------
__global__ __launch_bounds__(256) void k_q_attn(
        const ushort* __restrict__ xt, const ushort* __restrict__ Wqt,
        const float* __restrict__ bqkv, const ushort* __restrict__ SbT,
        ushort* __restrict__ attn) {
    const int nt = blockIdx.x, h = blockIdx.y, b = blockIdx.z;
    const int n0 = nt * 128;
    const int tid = threadIdx.x;
    const int w = tid >> 6, ln = tid & 63, lr = ln & 15, lq = ln >> 4;
    const int bh = b * H_ + h;
    const int lrow = ln >> 3, csw = (ln & 7) ^ lrow, sw = lr & 7;

    __shared__ __align__(16) char smem[49152];
    ushort* A0 = (ushort*)smem;                 // [128][64] xor-swz; also phi(q)/attn
    ushort* A1 = (ushort*)(smem + 16384);
    ushort* Q0 = (ushort*)(smem + 32768);       // [64][64] xor-swz
    ushort* Q1 = (ushort*)(smem + 40960);
    __shared__ __align__(16) ushort Sb[160][PADA];
    __shared__ float denL[128];

    // stage S (hi+lo)
    #pragma unroll
    for (int p = 0; p < 5; ++p) {
        int r = p * 32 + (tid >> 3);
        *(int4*)&Sb[r][(tid & 7) * 8] =
            *(const int4*)(SbT + (long)bh * 10240 + r * 64 + (tid & 7) * 8);
    }
    // preload epilogue bias into regs (keeps counted region pure of new loads;
    // pre-region loads are FIFO-oldest and retire at the first counted wait)
    float bsq[4];
    #pragma unroll
    for (int ji = 0; ji < 4; ++ji) bsq[ji] = bqkv[h * 64 + ji * 16 + lr];

    int gA[4], gB[2];
    #pragma unroll
    for (int i = 0; i < 4; ++i) {
        const int row = (w * 4 + i) * 8 + lrow;
        gA[i] = (b * N_ + n0 + row) * C_ + csw * 8;
    }
    #pragma unroll
    for (int i = 0; i < 2; ++i) {
        const int j = (w * 2 + i) * 8 + lrow;
        gB[i] = (h * 64 + j) * C_ + csw * 8;
    }

    const f32x4 FZ = {0.f, 0.f, 0.f, 0.f};
    f32x4 accq[2][4];
    #pragma unroll
    for (int mi = 0; mi < 2; mi++)
        #pragma unroll
        for (int ji = 0; ji < 4; ji++) accq[mi][ji] = FZ;

    auto stage = [&](ushort* Ab, ushort* Bb, int c0) {
        #pragma unroll
        for (int i = 0; i < 4; ++i)
            gld16(xt + gA[i] + c0, Ab + (w * 4 + i) * 512);
        #pragma unroll
        for (int i = 0; i < 2; ++i)
            gld16(Wqt + gB[i] + c0, Bb + (w * 2 + i) * 512);
    };
    auto compute = [&](const ushort* Ab, const ushort* Bb) {
        #pragma unroll
        for (int ks = 0; ks < 2; ++ks) {
            const int cof = ((ks * 4 + lq) ^ sw) * 8;
            bf16x8 a[2], bb[4];
            #pragma unroll
            for (int mi = 0; mi < 2; mi++)
                a[mi] = *(const bf16x8*)&Ab[(w * 32 + mi * 16 + lr) * 64 + cof];
            #pragma unroll
            for (int ji = 0; ji < 4; ji++)
                bb[ji] = *(const bf16x8*)&Bb[(ji * 16 + lr) * 64 + cof];
            #pragma unroll
            for (int mi = 0; mi < 2; mi++)
                #pragma unroll
                for (int ji = 0; ji < 4; ji++)
                    accq[mi][ji] = __builtin_amdgcn_mfma_f32_16x16x32_bf16(
                        a[mi], bb[ji], accq[mi][ji], 0, 0, 0);
        }
    };

    __syncthreads();   // Sb/bias staging drained; vmcnt clean before counted region
    stage(A0, Q0, 0);                      // c0 in flight (6 loads)
    #pragma unroll 1
    for (int kc = 0; kc < 6; kc += 2) {
        stage(A1, Q1, (kc + 1) * 64);      // +6 -> 12 outstanding
        VMCNT(6); SCHED0();                // oldest 6 (c_kc) landed
        BAR(); SCHED0();
        compute(A0, Q0);
        SCHED0(); BAR(); SCHED0();
        stage(A0, Q0, (kc + 2) * 64);
        VMCNT(6); SCHED0();
        BAR(); SCHED0();
        compute(A1, Q1);
        SCHED0(); BAR(); SCHED0();
    }
    stage(A1, Q1, 7 * 64);
    VMCNT(6); SCHED0();                    // c6 landed
    BAR(); SCHED0();
    compute(A0, Q0);
    SCHED0();
    VMCNT(0); SCHED0();                    // c7 landed
    BAR(); SCHED0();
    compute(A1, Q1);
    SCHED0();
    __syncthreads();                       // full fence before A0 reuse

    // phi(q) -> A0[n][d] (swizzled scalar writes, wave-private rows)
    #pragma unroll
    for (int mi = 0; mi < 2; mi++) {
        int nl = w * 32 + mi * 16 + lq * 4;
        #pragma unroll
        for (int ji = 0; ji < 4; ji++) {
            int d = ji * 16 + lr;
            #pragma unroll
            for (int r = 0; r < 4; r++) {
                int row = nl + r;
                A0[row * 64 + ((((d >> 3) ^ (row & 7)) << 3) | (d & 7))] =
                    f2bf(phi_f(accq[mi][ji][r] + bsq[ji]));
            }
        }
    }
    __syncthreads();
    // num (+den col 64) MFMA, hi+lo
    f32x4 accn[2][5];
    #pragma unroll
    for (int mi = 0; mi < 2; mi++)
        #pragma unroll
        for (int ei = 0; ei < 5; ei++) accn[mi][ei] = FZ;
    #pragma unroll
    for (int ks = 0; ks < 2; ++ks) {
        const int cof = ((ks * 4 + lq) ^ sw) * 8;
        bf16x8 a[2];
        #pragma unroll
        for (int mi = 0; mi < 2; mi++)
            a[mi] = *(const bf16x8*)&A0[(w * 32 + mi * 16 + lr) * 64 + cof];
        #pragma unroll
        for (int ei = 0; ei < 5; ei++) {
            bf16x8 bhi = *(const bf16x8*)&Sb[ei * 16 + lr][ks * 32 + lq * 8];
            bf16x8 blo = *(const bf16x8*)&Sb[80 + ei * 16 + lr][ks * 32 + lq * 8];
            #pragma unroll
            for (int mi = 0; mi < 2; mi++) {
                accn[mi][ei] = __builtin_amdgcn_mfma_f32_16x16x32_bf16(
                    a[mi], bhi, accn[mi][ei], 0, 0, 0);
                accn[mi][ei] = __builtin_amdgcn_mfma_f32_16x16x32_bf16(
                    a[mi], blo, accn[mi][ei], 0, 0, 0);
            }
        }
    }
    if (lr == 0) {
        #pragma unroll
        for (int mi = 0; mi < 2; mi++)
            #pragma unroll
            for (int r = 0; r < 4; r++)
                denL[w * 32 + mi * 16 + lq * 4 + r] = accn[mi][4][r] + EPS;
    }
    __syncthreads();
    // attn = num/den -> A0 (swizzled)
    #pragma unroll
    for (int mi = 0; mi < 2; mi++) {
        int nl = w * 32 + mi * 16 + lq * 4;
        #pragma unroll
        for (int ji = 0; ji < 4; ji++) {
            int e = ji * 16 + lr;
            #pragma unroll
            for (int r = 0; r < 4; r++) {
                int row = nl + r;
                A0[row * 64 + ((((e >> 3) ^ (row & 7)) << 3) | (e & 7))] =
                    f2bf(accn[mi][ji][r] / denL[row]);
            }
        }
    }
    __syncthreads();
    // coalesced store: attn ws [b][n][h*64 .. h*64+64)  (un-swizzle on read)
    {
        int row = tid >> 1, co = (tid & 1) * 32;
        int4* dp = (int4*)(attn + ((long)(b * N_ + n0 + row)) * C_ + h * 64 + co);
        #pragma unroll
        for (int k = 0; k < 4; ++k)
            dp[k] = *(const int4*)&A0[row * 64 + ((((co >> 3) + k) ^ (row & 7)) << 3)];
    }
}

// ---------------------------------------------------------------------------
// Proj GEMM: out[b][cout][n] = attn[n'][c] @ Wp_t[cout][c] + bias.
// grid (nt=512, jt=4), 128x128 tile.  HARDENED T3+T4 (r6 recipe, VMCNT(8)).
// ---------------------------------------------------------------------------
__global__ __launch_bounds__(256) void k_proj(
        const ushort* __restrict__ attn, const ushort* __restrict__ Wpt,
        const float* __restrict__ bproj, float* __restrict__ out) {
    const int nt = blockIdx.x, jt = blockIdx.y;
    const int tid = threadIdx.x;
    const int w = tid >> 6, ln = tid & 63, lr = ln & 15, lq = ln >> 4;
    const int b = nt >> 7;
    const int nloc = (nt & 127) * 128;
    const int lrow = ln >> 3, csw = (ln & 7) ^ lrow, sw = lr & 7;

    __shared__ __align__(16) char smem[65536];
    ushort* A0 = (ushort*)smem;
    ushort* B0 = (ushort*)(smem + 16384);
    ushort* A1 = (ushort*)(smem + 32768);
    ushort* B1 = (ushort*)(smem + 49152);
    float (*outT)[PADO] = (float(*)[PADO])smem;  // 64x132x4 = 33792 alias

    int gA[4], gB[4];
    #pragma unroll
    for (int i = 0; i < 4; ++i) {
        const int row = (w * 4 + i) * 8 + lrow;
        gA[i] = (nt * 128 + row) * C_ + csw * 8;
        gB[i] = (jt * 128 + row) * C_ + csw * 8;
    }
    // preload epilogue bias into regs
    float bsp[8];
    #pragma unroll
    for (int q = 0; q < 8; ++q)
        bsp[q] = bproj[jt * 128 + (q >> 2) * 64 + (q & 3) * 16 + lr];

    const f32x4 FZ = {0.f, 0.f, 0.f, 0.f};
    f32x4 acc[2][8];
    #pragma unroll
    for (int mi = 0; mi < 2; mi++)
        #pragma unroll
        for (int ji = 0; ji < 8; ji++) acc[mi][ji] = FZ;

    auto stage = [&](ushort* Ab, ushort* Bb, int c0) {
        #pragma unroll
        for (int i = 0; i < 4; ++i) {
            const int ch = w * 4 + i;
            gld16(attn + gA[i] + c0, Ab + ch * 512);
            gld16(Wpt + gB[i] + c0, Bb + ch * 512);
        }
    };
    auto compute = [&](const ushort* Ab, const ushort* Bb) {
        #pragma unroll
        for (int ks = 0; ks < 2; ++ks) {
            const int cof = ((ks * 4 + lq) ^ sw) * 8;
            bf16x8 a[2], bb[8];
            #pragma unroll
            for (int mi = 0; mi < 2; mi++)
                a[mi] = *(const bf16x8*)&Ab[(w * 32 + mi * 16 + lr) * 64 + cof];
            #pragma unroll
            for (int ji = 0; ji < 8; ji++)
                bb[ji] = *(const bf16x8*)&Bb[(ji * 16 + lr) * 64 + cof];
            #pragma unroll
            for (int mi = 0; mi < 2; mi++)
                #pragma unroll
                for (int ji = 0; ji < 8; ji++)
                    acc[mi][ji] = __builtin_amdgcn_mfma_f32_16x16x32_bf16(
                        a[mi], bb[ji], acc[mi][ji], 0, 0, 0);
        }
    };

    __syncthreads();   // vmcnt clean (bias preload retires at first counted wait)
    stage(A0, B0, 0);
    #pragma unroll 1
    for (int kc = 0; kc < 6; kc += 2) {
        stage(A1, B1, (kc + 1) * 64);
        VMCNT(8); SCHED0();
        BAR(); SCHED0();
        compute(A0, B0);
        SCHED0(); BAR(); SCHED0();
        stage(A0, B0, (kc + 2) * 64);
        VMCNT(8); SCHED0();
        BAR(); SCHED0();
        compute(A1, B1);
        SCHED0(); BAR(); SCHED0();
    }
    stage(A1, B1, 7 * 64);
    VMCNT(8); SCHED0();
    BAR(); SCHED0();
    compute(A0, B0);
    SCHED0();
    VMCNT(0); SCHED0();
    BAR(); SCHED0();
    compute(A1, B1);
    SCHED0();
    __syncthreads();                       // full fence before outT alias reuse

    #pragma unroll
    for (int half = 0; half < 2; ++half) {
        if (half) __syncthreads();
        #pragma unroll
        for (int mi = 0; mi < 2; mi++) {
            int nl = w * 32 + mi * 16 + lq * 4;
            #pragma unroll
            for (int ji = 0; ji < 4; ji++) {
                int cl = ji * 16 + lr;
                f32x4 v = acc[mi][half * 4 + ji];
                #pragma unroll
                for (int r = 0; r < 4; r++) v[r] += bsp[half * 4 + ji];
                *(f32x4*)&outT[cl][nl] = v;     // ds_write_b128
            }
        }
        __syncthreads();
        {
            int cl = tid >> 2, ch = (tid & 3) * 32;
            const float* sp = &outT[cl][ch];
            float* dp = out + ((long)(b * C_ + jt * 128 + half * 64 + cl)) * N_ + nloc + ch;
            #pragma unroll
            for (int k = 0; k < 8; ++k)
                ((float4*)dp)[k] = ((const float4*)sp)[k];
        }
    }
}

// ===========================================================================
// Round-1 fp32 fallback (used only if ws_size is too small for the MFMA path)
// ===========================================================================
__global__ __launch_bounds__(256) void kernelA_fb(
        const float* __restrict__ x, const float* __restrict__ Wqkv,
        const float* __restrict__ bqkv, float* __restrict__ S_g,
        float* __restrict__ ksum_g) {
    const int h = blockIdx.x;
    const int s = blockIdx.y;
    const int b = blockIdx.z;
    const int tid = threadIdx.x;
    const int tn = tid & 15;
    const int tj = tid >> 4;
    const int td = tid & 15;
    const int te = tid >> 4;

    __shared__ float As[16][64];
    __shared__ float Bs[16][128];
    __shared__ float kphi_s[64][64];
    __shared__ float v_s[64][64];

    float acc2[4][4];
    #pragma unroll
    for (int i = 0; i < 4; i++)
        #pragma unroll
        for (int j = 0; j < 4; j++) acc2[i][j] = 0.f;
    float ksum_r = 0.f;

    float bias_j[8];
    #pragma unroll
    for (int jj = 0; jj < 8; jj++) {
        int j = tj * 8 + jj;
        int col = (j < 64) ? (512 + h * 64 + j) : (1024 + h * 64 + (j - 64));
        bias_j[jj] = bqkv[col];
    }

    for (int it = 0; it < 8; ++it) {
        const int n0 = (s * 8 + it) * 64;
        float acc[4][8];
        #pragma unroll
        for (int i = 0; i < 4; i++)
            #pragma unroll
            for (int jj = 0; jj < 8; jj++) acc[i][jj] = 0.f;

        for (int kc = 0; kc < 32; ++kc) {
            const int c0 = kc * 16;
            __syncthreads();
            {
                int r = tid >> 4, n4 = (tid & 15) * 4;
                const float* src = x + ((size_t)b * C_ + (c0 + r)) * (size_t)N_ + n0 + n4;
                *(float4*)&As[r][n4] = *(const float4*)src;
            }
            #pragma unroll
            for (int part = 0; part < 2; ++part) {
                int idx = tid + part * 256;
                int r = idx >> 5;
                int j4 = (idx & 31) * 4;
                int col = (j4 < 64) ? (512 + h * 64 + j4) : (1024 + h * 64 + (j4 - 64));
                const float* src = Wqkv + (size_t)(c0 + r) * C3_ + col;
                *(float4*)&Bs[r][j4] = *(const float4*)src;
            }
            __syncthreads();
            #pragma unroll
            for (int k = 0; k < 16; ++k) {
                float a[4], bb[8];
                *(float4*)a      = *(const float4*)&As[k][tn * 4];
                *(float4*)&bb[0] = *(const float4*)&Bs[k][tj * 8];
                *(float4*)&bb[4] = *(const float4*)&Bs[k][tj * 8 + 4];
                #pragma unroll
                for (int i = 0; i < 4; i++)
                    #pragma unroll
                    for (int jj = 0; jj < 8; jj++)
                        acc[i][jj] = fmaf(a[i], bb[jj], acc[i][jj]);
            }
        }
        __syncthreads();
        if (tj < 8) {
            #pragma unroll
            for (int i = 0; i < 4; i++) {
                int n = tn * 4 + i;
                float tmp[8];
                #pragma unroll
                for (int jj = 0; jj < 8; jj++) tmp[jj] = phi_f(acc[i][jj] + bias_j[jj]);
                *(float4*)&kphi_s[n][tj * 8]     = *(float4*)&tmp[0];
                *(float4*)&kphi_s[n][tj * 8 + 4] = *(float4*)&tmp[4];
            }
        } else {
            #pragma unroll
            for (int i = 0; i < 4; i++) {
                int n = tn * 4 + i;
                float tmp[8];
                #pragma unroll
                for (int jj = 0; jj < 8; jj++) tmp[jj] = acc[i][jj] + bias_j[jj];
                *(float4*)&v_s[n][(tj - 8) * 8]     = *(float4*)&tmp[0];
                *(float4*)&v_s[n][(tj - 8) * 8 + 4] = *(float4*)&tmp[4];
            }
        }
        __syncthreads();
        #pragma unroll 4
        for (int n = 0; n < 64; ++n) {
            float a[4], bb[4];
            *(float4*)a  = *(const float4*)&kphi_s[n][td * 4];
            *(float4*)bb = *(const float4*)&v_s[n][te * 4];
            #pragma unroll
            for (int dd = 0; dd < 4; dd++)
                #pragma unroll
                for (int ee = 0; ee < 4; ee++)
                    acc2[dd][ee] = fmaf(a[dd], bb[ee], acc2[dd][ee]);
        }
        if (tid < 64) {
            float sum = 0.f;
            #pragma unroll 8
            for (int n = 0; n < 64; ++n) sum += kphi_s[n][tid];
            ksum_r += sum;
        }
    }

    const int bh = b * H_ + h;
    #pragma unroll
    for (int dd = 0; dd < 4; dd++)
        #pragma unroll
        for (int ee = 0; ee < 4; ee++)
            atomicAdd(&S_g[((size_t)bh * 64 + td * 4 + dd) * 64 + te * 4 + ee], acc2[dd][ee]);
    if (tid < 64) atomicAdd(&ksum_g[bh * 64 + tid], ksum_r);
}

__global__ __launch_bounds__(256) void kernelB_fb(
        const float* __restrict__ x, const float* __restrict__ Wqkv,
        const float* __restrict__ bqkv, const float* __restrict__ Wproj,
        const float* __restrict__ bproj, const float* __restrict__ S_g,
        const float* __restrict__ ksum_g, float* __restrict__ out) {
    const int nt = blockIdx.x;
    const int b  = blockIdx.y;
    const int n0 = nt * 16;
    const int tid = threadIdx.x;
    const int tn = tid & 3;
    const int tj = tid >> 2;

    __shared__ float QA[512][16];
    __shared__ float As[16][16];
    __shared__ float Bs2[16][256];
    __shared__ float SB[16][64];
    __shared__ float ksumL[512];
    __shared__ float denL[16];

    ksumL[tid]       = ksum_g[(size_t)b * 512 + tid];
    ksumL[tid + 256] = ksum_g[(size_t)b * 512 + tid + 256];

    for (int half = 0; half < 2; ++half) {
        float acc[4][4];
        #pragma unroll
        for (int i = 0; i < 4; i++)
            #pragma unroll
            for (int j = 0; j < 4; j++) acc[i][j] = 0.f;

        for (int kc = 0; kc < 32; ++kc) {
            const int c0 = kc * 16;
            __syncthreads();
            {
                int r = tid >> 4, n = tid & 15;
                As[r][n] = x[((size_t)b * C_ + c0 + r) * (size_t)N_ + n0 + n];
            }
            {
                int r = tid >> 4;
                int j0 = (tid & 15) * 16;
                const float* src = Wqkv + (size_t)(c0 + r) * C3_ + half * 256 + j0;
                float4* dst = (float4*)&Bs2[r][j0];
                #pragma unroll
                for (int q4 = 0; q4 < 4; q4++) dst[q4] = ((const float4*)src)[q4];
            }
            __syncthreads();
            #pragma unroll
            for (int k = 0; k < 16; ++k) {
                float a[4], bb[4];
                *(float4*)a  = *(const float4*)&As[k][tn * 4];
                *(float4*)bb = *(const float4*)&Bs2[k][tj * 4];
                #pragma unroll
                for (int i = 0; i < 4; i++)
                    #pragma unroll
                    for (int jj = 0; jj < 4; jj++)
                        acc[i][jj] = fmaf(a[i], bb[jj], acc[i][jj]);
            }
        }
        #pragma unroll
        for (int jj = 0; jj < 4; jj++) {
            int c = half * 256 + tj * 4 + jj;
            float bq = bqkv[c];
            float tmp[4];
            #pragma unroll
            for (int i = 0; i < 4; i++) tmp[i] = phi_f(acc[i][jj] + bq);
            *(float4*)&QA[c][tn * 4] = *(float4*)tmp;
        }
    }
    __syncthreads();

    for (int h = 0; h < H_; ++h) {
        if (tid < 16) {
            float d = 0.f;
            #pragma unroll 8
            for (int dd = 0; dd < 64; ++dd)
                d = fmaf(QA[h * 64 + dd][tid], ksumL[h * 64 + dd], d);
            denL[tid] = d + EPS;
        }
        float acc4[4] = {0.f, 0.f, 0.f, 0.f};
        for (int dc = 0; dc < 4; ++dc) {
            __syncthreads();
            {
                int r = tid >> 4, e4 = (tid & 15) * 4;
                *(float4*)&SB[r][e4] =
                    *(const float4*)&S_g[(((size_t)(b * H_ + h)) * 64 + dc * 16 + r) * 64 + e4];
            }
            __syncthreads();
            #pragma unroll
            for (int k = 0; k < 16; ++k) {
                float a[4];
                *(float4*)a = *(const float4*)&QA[h * 64 + dc * 16 + k][tn * 4];
                float bb = SB[k][tj];
                #pragma unroll
                for (int i = 0; i < 4; i++) acc4[i] = fmaf(a[i], bb, acc4[i]);
            }
        }
        __syncthreads();
        {
            float tmp[4];
            #pragma unroll
            for (int i = 0; i < 4; i++) tmp[i] = acc4[i] / denL[tn * 4 + i];
            *(float4*)&QA[h * 64 + tj][tn * 4] = *(float4*)tmp;
        }
        __syncthreads();
    }

    for (int half = 0; half < 2; ++half) {
        float acc[4][4];
        #pragma unroll
        for (int i = 0; i < 4; i++)
            #pragma unroll
            for (int j = 0; j < 4; j++) acc[i][j] = 0.f;

        for (int kc = 0; kc < 32; ++kc) {
            __syncthreads();
            {
                int r = tid >> 4;
                int j0 = (tid & 15) * 16;
                const float* src = Wproj + (size_t)(kc * 16 + r) * C_ + half * 256 + j0;
                float4* dst = (float4*)&Bs2[r][j0];
                #pragma unroll
                for (int q4 = 0; q4 < 4; q4++) dst[q4] = ((const float4*)src)[q4];
            }
            __syncthreads();
            #pragma unroll
            for (int k = 0; k < 16; ++k) {
                float a[4], bb[4];
                *(float4*)a  = *(const float4*)&QA[kc * 16 + k][tn * 4];
                *(float4*)bb = *(const float4*)&Bs2[k][tj * 4];
                #pragma unroll
                for (int i = 0; i < 4; i++)
                    #pragma unroll
                    for (int jj = 0; jj < 4; jj++)
                        acc[i][jj] = fmaf(a[i], bb[jj], acc[i][jj]);
            }
        }
        #pragma unroll
        for (int jj = 0; jj < 4; jj++) {
            int c = half * 256 + tj * 4 + jj;
            float bp = bproj[c];
            float tmp[4];
            #pragma unroll
            for (int i = 0; i < 4; i++) tmp[i] = acc[i][jj] + bp;
            *(float4*)&out[((size_t)b * C_ + c) * (size_t)N_ + n0 + tn * 4] = *(float4*)tmp;
        }
    }
}

// ===========================================================================
extern "C" void kernel_launch(void* const* d_in, const int* in_sizes, int n_in,
                              void* d_out, int out_size, void* d_ws, size_t ws_size,
                              hipStream_t stream) {
    const float* x     = (const float*)d_in[0];
    const float* Wqkv  = (const float*)d_in[1];
    const float* bqkv  = (const float*)d_in[2];
    const float* Wproj = (const float*)d_in[3];
    const float* bproj = (const float*)d_in[4];
    float* out = (float*)d_out;

    // ---- workspace layout (bytes) ----
    const size_t oS    = 0;                        // S_g f32 [32][64][64]   524288
    const size_t oK    = oS + 524288;              // ksum f32 [32][64]      8192
    const size_t oXT   = oK + 8192;                // xt bf16 [4][16384][512] 67108864
    const size_t oWq   = oXT + 67108864;           // Wq_t bf16 [1536][512]  1572864
    const size_t oWp   = oWq + 1572864;            // Wp_t bf16 [512][512]   524288
    const size_t oSbT  = oWp + 524288;             // SbT bf16 [32][160][64] 655360
    const size_t oAttn = oSbT + 655360;            // attn bf16 [4][16384][512] 67108864
    const size_t need  = oAttn + 67108864;         // = 137,502,720

    float* S_g    = (float*)((char*)d_ws + oS);
    float* ksum_g = (float*)((char*)d_ws + oK);

    if (ws_size < need) {
        // fp32 fallback (round-1 path)
        hipMemsetAsync(d_ws, 0, 532480, stream);
        kernelA_fb<<<dim3(H_, 32, B_), 256, 0, stream>>>(x, Wqkv, bqkv, S_g, ksum_g);
        kernelB_fb<<<dim3(N_ / 16, B_), 256, 0, stream>>>(x, Wqkv, bqkv, Wproj, bproj,
                                                          S_g, ksum_g, out);
        return;
    }

    ushort* xt   = (ushort*)((char*)d_ws + oXT);
    ushort* Wqt  = (ushort*)((char*)d_ws + oWq);
    ushort* Wpt  = (ushort*)((char*)d_ws + oWp);
    ushort* SbT  = (ushort*)((char*)d_ws + oSbT);
    ushort* attn = (ushort*)((char*)d_ws + oAttn);

    hipMemsetAsync(d_ws, 0, 532480, stream);  // S_g + ksum
    k_transpose<<<dim3(N_ / 64, C_ / 64, B_), 256, 0, stream>>>(
        x, xt, C_, N_, (long)C_ * N_, (long)N_ * C_);
    k_transpose<<<dim3(C3_ / 64, C_ / 64, 1), 256, 0, stream>>>(
        Wqkv, Wqt, C_, C3_, 0, 0);
    k_transpose<<<dim3(C_ / 64, C_ / 64, 1), 256, 0, stream>>>(
        Wproj, Wpt, C_, C_, 0, 0);
    k_kv_s<<<dim3(16, H_, B_), 256, 0, stream>>>(xt, Wqt, bqkv, S_g, ksum_g);
    k_sfin<<<dim3(B_ * H_), 256, 0, stream>>>(S_g, ksum_g, SbT);
    k_q_attn<<<dim3(N_ / 128, H_, B_), 256, 0, stream>>>(xt, Wqt, bqkv, SbT, attn);
    k_proj<<<dim3((B_ * N_) / 128, 4), 256, 0, stream>>>(attn, Wpt, bproj, out);
}